// Round 8
// baseline (344.975 us; speedup 1.0000x reference)
//
#include <hip/hip_runtime.h>
#include <hip/hip_bf16.h>

typedef __bf16 bf16_t;
typedef __bf16 bf16x2 __attribute__((ext_vector_type(2)));
typedef __bf16 bf16x4v __attribute__((ext_vector_type(4)));
typedef __bf16 bf16x8 __attribute__((ext_vector_type(8)));
typedef float f32x4 __attribute__((ext_vector_type(4)));

#define LOG2E 1.4426950408889634f
// (1/sqrt(128)) * log2(e), folded into Q at ln_rope time
#define QSCALE (0.08838834764831843f * 1.4426950408889634f)

// ---------------- fp32 -> bf16 conversion ----------------
__global__ __launch_bounds__(256) void cvt_f32_bf16(const float* __restrict__ in,
                                                    bf16_t* __restrict__ out, int n4) {
  int i = blockIdx.x * 256 + threadIdx.x;
  if (i < n4) {
    float4 v = ((const float4*)in)[i];
    bf16x4v o;
    o[0] = (__bf16)v.x; o[1] = (__bf16)v.y; o[2] = (__bf16)v.z; o[3] = (__bf16)v.w;
    *(bf16x4v*)(out + (size_t)i * 4) = o;
  }
}

// ---------------- RoPE cos/sin tables: [S=2048][64] ----------------
__global__ __launch_bounds__(256) void rope_tables(float* __restrict__ cosT,
                                                   float* __restrict__ sinT) {
  int idx = blockIdx.x * 256 + threadIdx.x;   // 2048*64 = 131072
  int s = idx >> 6, i = idx & 63;
  float inv = __builtin_amdgcn_exp2f(-(float)i * (19.931568569324174f / 64.0f));
  float f = (float)s * inv;
  cosT[idx] = cosf(f);
  sinT[idx] = sinf(f);
}

// ---------------- bf16 NT GEMM, phase-scheduled ----------------
template<int MI, int NI>
__global__ __launch_bounds__(512) void gemm8p(const bf16_t* __restrict__ A,
                                              const bf16_t* __restrict__ B,
                                              float* __restrict__ C,
                                              int M, int N, int K) {
  constexpr int BM = MI * 32;
  constexpr int BN = NI * 64;
  constexpr int NA = BM / 64;            // A stage insts per K-tile
  constexpr int NB = BN / 64;            // B stage insts per K-tile
  constexpr int ST = NA + NB;
  constexpr int PH = MI / 2;             // phases per K-tile (4 or 2)
  constexpr int stBase = ST / PH;
  constexpr int stFirst = ST - stBase * (PH - 1);   // == 3 for both configs
  static_assert(stFirst == 3, "vmcnt literal assumes 3 first-phase stages");

  __shared__ bf16_t LA[2][BM * 64];
  __shared__ bf16_t LB[2][BN * 64];

  int nb = N / BN;
  int cpx = gridDim.x >> 3;              // grid divisible by 8
  int bid = blockIdx.x;
  int swz = (bid & 7) * cpx + (bid >> 3);
  int bm = swz / nb, bn = swz % nb;
  int m0 = bm * BM, n0 = bn * BN;
  int tid = threadIdx.x, lane = tid & 63, wv = tid >> 6;
  int wr = wv >> 2, wc = wv & 3, lr = lane & 15, g = lane >> 4;
  int T = K >> 6;

  auto stageI = [&](int kt, int bi, int s) {
    int k0 = kt << 6;
    if (s < NA) {
      int c = s * 512 + tid;
      int row = c >> 3, lc = (c & 7) ^ (row & 7);
      __builtin_amdgcn_global_load_lds(
          (const __attribute__((address_space(1))) void*)(A + (size_t)(m0 + row) * K + k0 + lc * 8),
          (__attribute__((address_space(3))) void*)&LA[bi][(s * 512 + wv * 64) * 8], 16, 0, 0);
    } else {
      int c = (s - NA) * 512 + tid;
      int row = c >> 3, lc = (c & 7) ^ (row & 7);
      __builtin_amdgcn_global_load_lds(
          (const __attribute__((address_space(1))) void*)(B + (size_t)(n0 + row) * K + k0 + lc * 8),
          (__attribute__((address_space(3))) void*)&LB[bi][((s - NA) * 512 + wv * 64) * 8], 16, 0, 0);
    }
  };

  f32x4 acc[MI][NI];
#pragma unroll
  for (int i = 0; i < MI; i++)
#pragma unroll
    for (int j = 0; j < NI; j++)
#pragma unroll
      for (int r = 0; r < 4; r++) acc[i][j][r] = 0.f;

#pragma unroll
  for (int s = 0; s < ST; s++) stageI(0, 0, s);

  int ofk0 = ((0 + g) ^ (lr & 7)) << 3;
  int ofk1 = ((4 + g) ^ (lr & 7)) << 3;
  int offA = (wr * (MI * 16) + lr) * 64;
  int offB = (wc * (NI * 16) + lr) * 64;

  for (int t = 0; t < T; t++) {
    int bi = t & 1, bo = bi ^ 1;
    const bf16_t* la = LA[bi];
    const bf16_t* lb = LB[bi];
    bool pre = (t + 1 < T);
    bf16x8 bq[NI];
#pragma unroll
    for (int ph = 0; ph < PH; ph++) {
      const int s0 = (ph == 0) ? 0 : stFirst + (ph - 1) * stBase;
      const int sc = (ph == 0) ? stFirst : stBase;
      if (pre) {
#pragma unroll
        for (int s = s0; s < s0 + sc; s++) stageI(t + 1, bo, s);
      }
      if (ph == 0) {
        if (pre) asm volatile("s_waitcnt vmcnt(3)" ::: "memory");
        else     asm volatile("s_waitcnt vmcnt(0)" ::: "memory");
        __builtin_amdgcn_s_barrier();
        asm volatile("" ::: "memory");
      }
      const int ks = (PH == 4) ? (ph >> 1) : ph;
      const int q  = (PH == 4) ? (ph & 1) : 0;
      const bool rb = (PH == 2) || ((ph & 1) == 0);
      const int ofk = ks ? ofk1 : ofk0;
      bf16x8 af[4];
#pragma unroll
      for (int i = 0; i < 4; i++)
        af[i] = *(const bf16x8*)&la[offA + (q * 4 + i) * 1024 + ofk];
      if (rb) {
#pragma unroll
        for (int ni = 0; ni < NI; ni++)
          bq[ni] = *(const bf16x8*)&lb[offB + ni * 1024 + ofk];
      }
      if (ph != 0) {
        asm volatile("" ::: "memory");
        __builtin_amdgcn_s_barrier();
        asm volatile("" ::: "memory");
      }
      __builtin_amdgcn_s_setprio(1);
#pragma unroll
      for (int i = 0; i < 4; i++)
#pragma unroll
        for (int ni = 0; ni < NI; ni++)
          acc[q * 4 + i][ni] =
              __builtin_amdgcn_mfma_f32_16x16x32_bf16(af[i], bq[ni], acc[q * 4 + i][ni], 0, 0, 0);
      __builtin_amdgcn_s_setprio(0);
      asm volatile("s_waitcnt lgkmcnt(0)" ::: "memory");
      __builtin_amdgcn_s_barrier();
      asm volatile("" ::: "memory");
    }
  }

#pragma unroll
  for (int mi = 0; mi < MI; mi++)
#pragma unroll
    for (int ni = 0; ni < NI; ni++) {
      int m = m0 + wr * (MI * 16) + mi * 16 + g * 4;
      int n = n0 + wc * (NI * 16) + ni * 16 + lr;
#pragma unroll
      for (int r = 0; r < 4; r++) C[(size_t)(m + r) * N + n] = acc[mi][ni][r];
    }
}

// ---------------- fused per-head LayerNorm + RoPE -> bf16 Q(B,H,S,D), K(B,KV,S,D) ----
__global__ __launch_bounds__(256) void ln_rope(const float* __restrict__ qkv,
                                               const float* __restrict__ qw, const float* __restrict__ qb,
                                               const float* __restrict__ kw, const float* __restrict__ kb,
                                               const float* __restrict__ cosT, const float* __restrict__ sinT,
                                               bf16_t* __restrict__ Qr, bf16_t* __restrict__ Kr) {
  int row = blockIdx.x;              // b*2048 + s
  int b = row >> 11, s = row & 2047;
  int lane = threadIdx.x & 63, wv = threadIdx.x >> 6;
  float c = cosT[(s << 6) + lane], sn = sinT[(s << 6) + lane];
  const float* base = qkv + (size_t)row * 5120;
#pragma unroll
  for (int i = 0; i < 5; i++) {
    int head = wv * 5 + i;           // 0..15 = q heads, 16..19 = k heads
    bool isq = head < 16;
    int off = isq ? (head << 7) : (4096 + ((head - 16) << 7));
    float2 x = *(const float2*)(base + off + (lane << 1));
    float sum = x.x + x.y;
#pragma unroll
    for (int m = 1; m < 64; m <<= 1) sum += __shfl_xor(sum, m);
    float mu = sum * 0.0078125f;
    float x0 = x.x - mu, x1 = x.y - mu;
    float vs = x0 * x0 + x1 * x1;
#pragma unroll
    for (int m = 1; m < 64; m <<= 1) vs += __shfl_xor(vs, m);
    float rs = rsqrtf(vs * 0.0078125f + 1e-6f);
    const float* w = isq ? qw : kw;
    const float* bb = isq ? qb : kb;
    float y0 = x0 * rs * w[lane << 1] + bb[lane << 1];
    float y1 = x1 * rs * w[(lane << 1) + 1] + bb[(lane << 1) + 1];
    float o0 = y0 * c - y1 * sn;
    float o1 = y0 * sn + y1 * c;
    if (isq) { o0 *= QSCALE; o1 *= QSCALE; }
    bf16x2 ov; ov[0] = (__bf16)o0; ov[1] = (__bf16)o1;
    size_t dst = isq ? ((((size_t)(b * 16 + head)) * 2048 + s) * 128 + (lane << 1))
                     : ((((size_t)(b * 4 + (head - 16))) * 2048 + s) * 128 + (lane << 1));
    *(bf16x2*)((isq ? Qr : Kr) + dst) = ov;
  }
}

// ---------------- V transpose: qkv v-slice (B,S,KV,D) -> Vt (B,KV,D,S) bf16 -------
__global__ __launch_bounds__(256) void vtrans(const float* __restrict__ qkv,
                                              bf16_t* __restrict__ Vt) {
  int bid = blockIdx.x;              // ((b*4+kv)*64 + sb)
  int sb = bid & 63, kv = (bid >> 6) & 3, b = bid >> 8;
  int s0 = sb << 5;
  __shared__ bf16_t T[128 * 33];
  int tid = threadIdx.x;
#pragma unroll
  for (int i = 0; i < 16; i++) {
    int idx = i * 256 + tid;         // 0..4095
    int r = idx >> 7, d = idx & 127;
    float v = qkv[((size_t)(b * 2048 + s0 + r)) * 5120 + 4608 + (kv << 7) + d];
    T[d * 33 + r] = (__bf16)v;
  }
  __syncthreads();
#pragma unroll
  for (int j = 0; j < 16; j++) {
    int idx = j * 256 + tid;
    int d = idx >> 5, sc = idx & 31;
    Vt[(((size_t)(b * 4 + kv)) * 128 + d) * 2048 + s0 + sc] = T[d * 33 + sc];
  }
}

// ---------------- causal GQA flash attention + sigmoid gate -> ag bf16 (B,S,H*D) ----
// Block = (h, b, qg): 4 waves split the kv range [0, qg+1) into 4 contiguous
// chunks (equal work -> waves retire together); grid dispatched longest-qg-first
// (LPT backfill). Partials (O, m, l) merged 4-way through LDS at the end.
// Inner half-tile code identical to the verified R4-R7 kernel.
__global__ __launch_bounds__(256) void attn(const bf16_t* __restrict__ Qr,
                                            const bf16_t* __restrict__ Kr,
                                            const bf16_t* __restrict__ Vt,
                                            const float* __restrict__ qkv,
                                            bf16_t* __restrict__ ag) {
  __shared__ float Ols[4][32][132];     // 67.6 KB, +4 f32 pad per row
  __shared__ float Mls[4][32];
  __shared__ float Lls[4][32];
  int bid = blockIdx.x;                 // 2048 = 64qg * (16h * 2b), longest first
  int h = bid & 15, b = (bid >> 4) & 1;
  int qg = 63 - (bid >> 5);
  int kvh = h >> 2;
  int tid = threadIdx.x, lane = tid & 63, wv = tid >> 6;
  int lr = lane & 15, g = lane >> 4;
  int qw = qg << 5;
  int qrow0 = qw + lr, qrow1 = qrow0 + 16;
  int n = qg + 1;                       // kv half-tiles total
  int c0 = (n * wv) >> 2, c1 = (n * (wv + 1)) >> 2;   // this wave's chunk

  const bf16_t* Qg0 = Qr + (((size_t)(b * 16 + h)) * 2048 + qrow0) * 128;
  bf16x8 qf0[4], qf1[4];
#pragma unroll
  for (int ds = 0; ds < 4; ds++) {
    qf0[ds] = *(const bf16x8*)(Qg0 + ds * 32 + g * 8);
    qf1[ds] = *(const bf16x8*)(Qg0 + 16 * 128 + ds * 32 + g * 8);
  }
  const bf16_t* Kg = Kr + ((size_t)(b * 4 + kvh)) * 2048 * 128;
  const bf16_t* Vg = Vt + ((size_t)(b * 4 + kvh)) * 128 * 2048;

  f32x4 oa0[8], oa1[8];
#pragma unroll
  for (int i = 0; i < 8; i++)
#pragma unroll
    for (int r = 0; r < 4; r++) { oa0[i][r] = 0.f; oa1[i][r] = 0.f; }
  float mrun0 = -1e30f, mrun1 = -1e30f, lsp0 = 0.f, lsp1 = 0.f;

  int r0base = ((lr >> 2) << 3) + (lr & 3);       // pi(lr): A-row -> K-row map
  int kvlane = g << 3;

  bf16x8 kA[8], kB[8], va[8];

  auto loadK = [&](bf16x8 (&ka)[8], int kvb) {
    const bf16_t* kp = Kg + (size_t)(kvb + r0base) * 128 + g * 8;
#pragma unroll
    for (int ds = 0; ds < 4; ds++) {
      ka[ds]     = *(const bf16x8*)(kp + ds * 32);
      ka[4 + ds] = *(const bf16x8*)(kp + 4 * 128 + ds * 32);
    }
  };

  auto sm = [&](const f32x4& s0, const f32x4& s1, int qrow, int kvabs, bool dia,
                float& mrun, float& lsp, bf16x8& pb, f32x4 (&oac)[8]) {
    float tt[8];
#pragma unroll
    for (int r = 0; r < 4; r++) { tt[r] = s0[r]; tt[4 + r] = s1[r]; }
    if (dia) {
#pragma unroll
      for (int r = 0; r < 4; r++) {
        if (kvabs + r > qrow)     tt[r]     = -1e30f;
        if (kvabs + 4 + r > qrow) tt[4 + r] = -1e30f;
      }
    }
    float lm = fmaxf(fmaxf(fmaxf(tt[0], tt[1]), tt[2]),
                     fmaxf(fmaxf(tt[3], tt[4]), fmaxf(fmaxf(tt[5], tt[6]), tt[7])));
    if (__all(lm <= mrun + 8.f)) {      // defer-max common path: lane-local only
      float ps = 0.f;
#pragma unroll
      for (int i = 0; i < 8; i++) {
        float pv = __builtin_amdgcn_exp2f(tt[i] - mrun);
        pb[i] = (__bf16)pv; ps += pv;
      }
      lsp += ps;
    } else {                            // rare rescale path
      float pm = lm;
      pm = fmaxf(pm, __shfl_xor(pm, 16));
      pm = fmaxf(pm, __shfl_xor(pm, 32));
      float mnew = fmaxf(mrun, pm);
      float corr = __builtin_amdgcn_exp2f(mrun - mnew);
      float ps = 0.f;
#pragma unroll
      for (int i = 0; i < 8; i++) {
        float pv = __builtin_amdgcn_exp2f(tt[i] - mnew);
        pb[i] = (__bf16)pv; ps += pv;
      }
      lsp = lsp * corr + ps;
      mrun = mnew;
#pragma unroll
      for (int dt = 0; dt < 8; dt++)
#pragma unroll
        for (int r = 0; r < 4; r++) oac[dt][r] *= corr;
    }
  };

  auto half = [&](bf16x8 (&ka)[8], int hh) {
    int kvb = hh << 5;
    const bf16_t* vp = Vg + (size_t)lr * 2048 + kvb + g * 8;
#pragma unroll
    for (int dt = 0; dt < 8; dt++)
      va[dt] = *(const bf16x8*)(vp + (size_t)dt * 16 * 2048);
    f32x4 s00, s10, s01, s11;
#pragma unroll
    for (int r = 0; r < 4; r++) { s00[r] = 0.f; s10[r] = 0.f; s01[r] = 0.f; s11[r] = 0.f; }
    __builtin_amdgcn_s_setprio(1);
#pragma unroll
    for (int ds = 0; ds < 4; ds++) {
      s00 = __builtin_amdgcn_mfma_f32_16x16x32_bf16(ka[ds],     qf0[ds], s00, 0, 0, 0);
      s10 = __builtin_amdgcn_mfma_f32_16x16x32_bf16(ka[4 + ds], qf0[ds], s10, 0, 0, 0);
      s01 = __builtin_amdgcn_mfma_f32_16x16x32_bf16(ka[ds],     qf1[ds], s01, 0, 0, 0);
      s11 = __builtin_amdgcn_mfma_f32_16x16x32_bf16(ka[4 + ds], qf1[ds], s11, 0, 0, 0);
    }
    __builtin_amdgcn_s_setprio(0);
    int kvabs = kvb + kvlane;
    bool dia = (hh == qg);
    bf16x8 pb0, pb1;
    sm(s00, s10, qrow0, kvabs, dia, mrun0, lsp0, pb0, oa0);
    sm(s01, s11, qrow1, kvabs, dia, mrun1, lsp1, pb1, oa1);
    __builtin_amdgcn_s_setprio(1);
#pragma unroll
    for (int dt = 0; dt < 8; dt++) {
      oa0[dt] = __builtin_amdgcn_mfma_f32_16x16x32_bf16(va[dt], pb0, oa0[dt], 0, 0, 0);
      oa1[dt] = __builtin_amdgcn_mfma_f32_16x16x32_bf16(va[dt], pb1, oa1[dt], 0, 0, 0);
    }
    __builtin_amdgcn_s_setprio(0);
  };

  if (c0 < c1) {
    loadK(kA, c0 << 5);
    int hh = c0;
    for (; hh + 1 < c1; hh += 2) {
      loadK(kB, (hh + 1) << 5);
      half(kA, hh);
      if (hh + 2 < c1) loadK(kA, (hh + 2) << 5);
      half(kB, hh + 1);
    }
    if (hh < c1) half(kA, hh);
  }

  // per-row l partial reduce (row-uniform after 2 shfls)
  float ls0 = lsp0 + __shfl_xor(lsp0, 16);
  ls0 += __shfl_xor(ls0, 32);
  float ls1 = lsp1 + __shfl_xor(lsp1, 16);
  ls1 += __shfl_xor(ls1, 32);

  // write partials to LDS
#pragma unroll
  for (int dt = 0; dt < 8; dt++) {
    *(f32x4*)&Ols[wv][lr][dt * 16 + g * 4]      = oa0[dt];
    *(f32x4*)&Ols[wv][lr + 16][dt * 16 + g * 4] = oa1[dt];
  }
  if (lane < 16) {                      // lane == lr, g == 0 holds rows lr / lr+16
    Mls[wv][lane] = mrun0;      Lls[wv][lane] = ls0;
    Mls[wv][lane + 16] = mrun1; Lls[wv][lane + 16] = ls1;
  }
  __syncthreads();

  // merge: wave wv handles rows [8wv, 8wv+8); lane -> (row, 16-d chunk)
  int row = wv * 8 + (lane >> 3);
  int dc = lane & 7;
  float m0 = Mls[0][row], m1 = Mls[1][row], m2 = Mls[2][row], m3 = Mls[3][row];
  float mm = fmaxf(fmaxf(m0, m1), fmaxf(m2, m3));
  float s0 = __builtin_amdgcn_exp2f(m0 - mm);
  float s1 = __builtin_amdgcn_exp2f(m1 - mm);
  float s2 = __builtin_amdgcn_exp2f(m2 - mm);
  float s3 = __builtin_amdgcn_exp2f(m3 - mm);
  float ll = Lls[0][row] * s0 + Lls[1][row] * s1 + Lls[2][row] * s2 + Lls[3][row] * s3;
  float invl = __builtin_amdgcn_rcpf(ll);
  size_t grow = (size_t)(b * 2048 + qw + row);
  const float* gp = qkv + grow * 5120 + 2048 + (h << 7) + dc * 16;
  bf16_t* op = ag + grow * 2048 + (h << 7) + dc * 16;
#pragma unroll
  for (int j = 0; j < 4; j++) {
    f32x4 a0 = *(const f32x4*)&Ols[0][row][dc * 16 + j * 4];
    f32x4 a1 = *(const f32x4*)&Ols[1][row][dc * 16 + j * 4];
    f32x4 a2 = *(const f32x4*)&Ols[2][row][dc * 16 + j * 4];
    f32x4 a3 = *(const f32x4*)&Ols[3][row][dc * 16 + j * 4];
    float4 gt = *(const float4*)(gp + j * 4);
    bf16x4v o;
    float v0 = (a0[0] * s0 + a1[0] * s1 + a2[0] * s2 + a3[0] * s3) * invl;
    float v1 = (a0[1] * s0 + a1[1] * s1 + a2[1] * s2 + a3[1] * s3) * invl;
    float v2 = (a0[2] * s0 + a1[2] * s1 + a2[2] * s2 + a3[2] * s3) * invl;
    float v3 = (a0[3] * s0 + a1[3] * s1 + a2[3] * s2 + a3[3] * s3) * invl;
    o[0] = (__bf16)(v0 * __builtin_amdgcn_rcpf(1.f + __builtin_amdgcn_exp2f(-gt.x * LOG2E)));
    o[1] = (__bf16)(v1 * __builtin_amdgcn_rcpf(1.f + __builtin_amdgcn_exp2f(-gt.y * LOG2E)));
    o[2] = (__bf16)(v2 * __builtin_amdgcn_rcpf(1.f + __builtin_amdgcn_exp2f(-gt.z * LOG2E)));
    o[3] = (__bf16)(v3 * __builtin_amdgcn_rcpf(1.f + __builtin_amdgcn_exp2f(-gt.w * LOG2E)));
    *(bf16x4v*)(op + j * 4) = o;
  }
}

// ---------------- launch ----------------
extern "C" void kernel_launch(void* const* d_in, const int* in_sizes, int n_in,
                              void* d_out, int out_size, void* d_ws, size_t ws_size,
                              hipStream_t stream) {
  const float* x    = (const float*)d_in[0];
  const float* wqkv = (const float*)d_in[1];
  const float* wo   = (const float*)d_in[2];
  const float* qnw  = (const float*)d_in[3];
  const float* qnb  = (const float*)d_in[4];
  const float* knw  = (const float*)d_in[5];
  const float* knb  = (const float*)d_in[6];
  float* out = (float*)d_out;

  char* p = (char*)d_ws;
  bf16_t* xb  = (bf16_t*)p;           // 16 MB, reused as ag after GEMM1
  bf16_t* ag  = xb;
  p += (size_t)16777216;
  bf16_t* wqb = (bf16_t*)p;           // 20 MB, reused as Qr after GEMM1
  bf16_t* Qr  = wqb;
  p += (size_t)20971520;
  bf16_t* wob = (bf16_t*)p; p += (size_t)8388608;
  float*  qkv = (float*)p;  p += (size_t)83886080;
  bf16_t* Kr  = (bf16_t*)p; p += (size_t)4194304;
  bf16_t* Vt  = (bf16_t*)p; p += (size_t)4194304;
  float* cosT = (float*)p;  p += (size_t)524288;
  float* sinT = (float*)p;  p += (size_t)524288;

  cvt_f32_bf16<<<8192, 256, 0, stream>>>(x, xb, 2097152);
  cvt_f32_bf16<<<10240, 256, 0, stream>>>(wqkv, wqb, 2621440);
  cvt_f32_bf16<<<4096, 256, 0, stream>>>(wo, wob, 1048576);
  rope_tables<<<512, 256, 0, stream>>>(cosT, sinT);

  // qkv = x @ w_qkv^T   (4096 x 5120 x K=2048): BM=256, BN=320 -> 256 blocks
  gemm8p<8, 5><<<256, 512, 0, stream>>>(xb, wqb, qkv, 4096, 5120, 2048);

  ln_rope<<<4096, 256, 0, stream>>>(qkv, qnw, qnb, knw, knb, cosT, sinT, Qr, Kr);
  vtrans<<<512, 256, 0, stream>>>(qkv, Vt);

  attn<<<2048, 256, 0, stream>>>(Qr, Kr, Vt, qkv, ag);

  // out = ag @ w_o^T    (4096 x 2048 x K=2048): BM=128, BN=256 -> 256 blocks
  gemm8p<4, 4><<<256, 512, 0, stream>>>(ag, wob, out, 4096, 2048, 2048);
}

// Round 9
// 336.840 us; speedup vs baseline: 1.0241x; 1.0241x over previous
//
#include <hip/hip_runtime.h>
#include <hip/hip_bf16.h>

typedef __bf16 bf16_t;
typedef __bf16 bf16x2 __attribute__((ext_vector_type(2)));
typedef __bf16 bf16x4v __attribute__((ext_vector_type(4)));
typedef __bf16 bf16x8 __attribute__((ext_vector_type(8)));
typedef float f32x4 __attribute__((ext_vector_type(4)));

#define LOG2E 1.4426950408889634f
// (1/sqrt(128)) * log2(e), folded into Q at ln_rope time
#define QSCALE (0.08838834764831843f * 1.4426950408889634f)

// ---------------- fp32 -> bf16 conversion ----------------
__global__ __launch_bounds__(256) void cvt_f32_bf16(const float* __restrict__ in,
                                                    bf16_t* __restrict__ out, int n4) {
  int i = blockIdx.x * 256 + threadIdx.x;
  if (i < n4) {
    float4 v = ((const float4*)in)[i];
    bf16x4v o;
    o[0] = (__bf16)v.x; o[1] = (__bf16)v.y; o[2] = (__bf16)v.z; o[3] = (__bf16)v.w;
    *(bf16x4v*)(out + (size_t)i * 4) = o;
  }
}

// ---------------- RoPE cos/sin tables: [S=2048][64] ----------------
__global__ __launch_bounds__(256) void rope_tables(float* __restrict__ cosT,
                                                   float* __restrict__ sinT) {
  int idx = blockIdx.x * 256 + threadIdx.x;   // 2048*64 = 131072
  int s = idx >> 6, i = idx & 63;
  float inv = __builtin_amdgcn_exp2f(-(float)i * (19.931568569324174f / 64.0f));
  float f = (float)s * inv;
  cosT[idx] = cosf(f);
  sinT[idx] = sinf(f);
}

// ---------------- bf16 NT GEMM, phase-scheduled ----------------
template<int MI, int NI>
__global__ __launch_bounds__(512) void gemm8p(const bf16_t* __restrict__ A,
                                              const bf16_t* __restrict__ B,
                                              float* __restrict__ C,
                                              int M, int N, int K) {
  constexpr int BM = MI * 32;
  constexpr int BN = NI * 64;
  constexpr int NA = BM / 64;            // A stage insts per K-tile
  constexpr int NB = BN / 64;            // B stage insts per K-tile
  constexpr int ST = NA + NB;
  constexpr int PH = MI / 2;             // phases per K-tile (4 or 2)
  constexpr int stBase = ST / PH;
  constexpr int stFirst = ST - stBase * (PH - 1);   // == 3 for both configs
  static_assert(stFirst == 3, "vmcnt literal assumes 3 first-phase stages");

  __shared__ bf16_t LA[2][BM * 64];
  __shared__ bf16_t LB[2][BN * 64];

  int nb = N / BN;
  int cpx = gridDim.x >> 3;              // grid divisible by 8
  int bid = blockIdx.x;
  int swz = (bid & 7) * cpx + (bid >> 3);
  int bm = swz / nb, bn = swz % nb;
  int m0 = bm * BM, n0 = bn * BN;
  int tid = threadIdx.x, lane = tid & 63, wv = tid >> 6;
  int wr = wv >> 2, wc = wv & 3, lr = lane & 15, g = lane >> 4;
  int T = K >> 6;

  auto stageI = [&](int kt, int bi, int s) {
    int k0 = kt << 6;
    if (s < NA) {
      int c = s * 512 + tid;
      int row = c >> 3, lc = (c & 7) ^ (row & 7);
      __builtin_amdgcn_global_load_lds(
          (const __attribute__((address_space(1))) void*)(A + (size_t)(m0 + row) * K + k0 + lc * 8),
          (__attribute__((address_space(3))) void*)&LA[bi][(s * 512 + wv * 64) * 8], 16, 0, 0);
    } else {
      int c = (s - NA) * 512 + tid;
      int row = c >> 3, lc = (c & 7) ^ (row & 7);
      __builtin_amdgcn_global_load_lds(
          (const __attribute__((address_space(1))) void*)(B + (size_t)(n0 + row) * K + k0 + lc * 8),
          (__attribute__((address_space(3))) void*)&LB[bi][((s - NA) * 512 + wv * 64) * 8], 16, 0, 0);
    }
  };

  f32x4 acc[MI][NI];
#pragma unroll
  for (int i = 0; i < MI; i++)
#pragma unroll
    for (int j = 0; j < NI; j++)
#pragma unroll
      for (int r = 0; r < 4; r++) acc[i][j][r] = 0.f;

#pragma unroll
  for (int s = 0; s < ST; s++) stageI(0, 0, s);

  int ofk0 = ((0 + g) ^ (lr & 7)) << 3;
  int ofk1 = ((4 + g) ^ (lr & 7)) << 3;
  int offA = (wr * (MI * 16) + lr) * 64;
  int offB = (wc * (NI * 16) + lr) * 64;

  for (int t = 0; t < T; t++) {
    int bi = t & 1, bo = bi ^ 1;
    const bf16_t* la = LA[bi];
    const bf16_t* lb = LB[bi];
    bool pre = (t + 1 < T);
    bf16x8 bq[NI];
#pragma unroll
    for (int ph = 0; ph < PH; ph++) {
      const int s0 = (ph == 0) ? 0 : stFirst + (ph - 1) * stBase;
      const int sc = (ph == 0) ? stFirst : stBase;
      if (pre) {
#pragma unroll
        for (int s = s0; s < s0 + sc; s++) stageI(t + 1, bo, s);
      }
      if (ph == 0) {
        if (pre) asm volatile("s_waitcnt vmcnt(3)" ::: "memory");
        else     asm volatile("s_waitcnt vmcnt(0)" ::: "memory");
        __builtin_amdgcn_s_barrier();
        asm volatile("" ::: "memory");
      }
      const int ks = (PH == 4) ? (ph >> 1) : ph;
      const int q  = (PH == 4) ? (ph & 1) : 0;
      const bool rb = (PH == 2) || ((ph & 1) == 0);
      const int ofk = ks ? ofk1 : ofk0;
      bf16x8 af[4];
#pragma unroll
      for (int i = 0; i < 4; i++)
        af[i] = *(const bf16x8*)&la[offA + (q * 4 + i) * 1024 + ofk];
      if (rb) {
#pragma unroll
        for (int ni = 0; ni < NI; ni++)
          bq[ni] = *(const bf16x8*)&lb[offB + ni * 1024 + ofk];
      }
      if (ph != 0) {
        asm volatile("" ::: "memory");
        __builtin_amdgcn_s_barrier();
        asm volatile("" ::: "memory");
      }
      __builtin_amdgcn_s_setprio(1);
#pragma unroll
      for (int i = 0; i < 4; i++)
#pragma unroll
        for (int ni = 0; ni < NI; ni++)
          acc[q * 4 + i][ni] =
              __builtin_amdgcn_mfma_f32_16x16x32_bf16(af[i], bq[ni], acc[q * 4 + i][ni], 0, 0, 0);
      __builtin_amdgcn_s_setprio(0);
      asm volatile("s_waitcnt lgkmcnt(0)" ::: "memory");
      __builtin_amdgcn_s_barrier();
      asm volatile("" ::: "memory");
    }
  }

#pragma unroll
  for (int mi = 0; mi < MI; mi++)
#pragma unroll
    for (int ni = 0; ni < NI; ni++) {
      int m = m0 + wr * (MI * 16) + mi * 16 + g * 4;
      int n = n0 + wc * (NI * 16) + ni * 16 + lr;
#pragma unroll
      for (int r = 0; r < 4; r++) C[(size_t)(m + r) * N + n] = acc[mi][ni][r];
    }
}

// ---------------- fused per-head LayerNorm + RoPE -> bf16 Q(B,H,S,D), K(B,KV,S,D) ----
__global__ __launch_bounds__(256) void ln_rope(const float* __restrict__ qkv,
                                               const float* __restrict__ qw, const float* __restrict__ qb,
                                               const float* __restrict__ kw, const float* __restrict__ kb,
                                               const float* __restrict__ cosT, const float* __restrict__ sinT,
                                               bf16_t* __restrict__ Qr, bf16_t* __restrict__ Kr) {
  int row = blockIdx.x;              // b*2048 + s
  int b = row >> 11, s = row & 2047;
  int lane = threadIdx.x & 63, wv = threadIdx.x >> 6;
  float c = cosT[(s << 6) + lane], sn = sinT[(s << 6) + lane];
  const float* base = qkv + (size_t)row * 5120;
#pragma unroll
  for (int i = 0; i < 5; i++) {
    int head = wv * 5 + i;           // 0..15 = q heads, 16..19 = k heads
    bool isq = head < 16;
    int off = isq ? (head << 7) : (4096 + ((head - 16) << 7));
    float2 x = *(const float2*)(base + off + (lane << 1));
    float sum = x.x + x.y;
#pragma unroll
    for (int m = 1; m < 64; m <<= 1) sum += __shfl_xor(sum, m);
    float mu = sum * 0.0078125f;
    float x0 = x.x - mu, x1 = x.y - mu;
    float vs = x0 * x0 + x1 * x1;
#pragma unroll
    for (int m = 1; m < 64; m <<= 1) vs += __shfl_xor(vs, m);
    float rs = rsqrtf(vs * 0.0078125f + 1e-6f);
    const float* w = isq ? qw : kw;
    const float* bb = isq ? qb : kb;
    float y0 = x0 * rs * w[lane << 1] + bb[lane << 1];
    float y1 = x1 * rs * w[(lane << 1) + 1] + bb[(lane << 1) + 1];
    float o0 = y0 * c - y1 * sn;
    float o1 = y0 * sn + y1 * c;
    if (isq) { o0 *= QSCALE; o1 *= QSCALE; }
    bf16x2 ov; ov[0] = (__bf16)o0; ov[1] = (__bf16)o1;
    size_t dst = isq ? ((((size_t)(b * 16 + head)) * 2048 + s) * 128 + (lane << 1))
                     : ((((size_t)(b * 4 + (head - 16))) * 2048 + s) * 128 + (lane << 1));
    *(bf16x2*)((isq ? Qr : Kr) + dst) = ov;
  }
}

// ---------------- V transpose: qkv v-slice (B,S,KV,D) -> Vt (B,KV,D,S) bf16 -------
__global__ __launch_bounds__(256) void vtrans(const float* __restrict__ qkv,
                                              bf16_t* __restrict__ Vt) {
  int bid = blockIdx.x;              // ((b*4+kv)*64 + sb)
  int sb = bid & 63, kv = (bid >> 6) & 3, b = bid >> 8;
  int s0 = sb << 5;
  __shared__ bf16_t T[128 * 33];
  int tid = threadIdx.x;
#pragma unroll
  for (int i = 0; i < 16; i++) {
    int idx = i * 256 + tid;         // 0..4095
    int r = idx >> 7, d = idx & 127;
    float v = qkv[((size_t)(b * 2048 + s0 + r)) * 5120 + 4608 + (kv << 7) + d];
    T[d * 33 + r] = (__bf16)v;
  }
  __syncthreads();
#pragma unroll
  for (int j = 0; j < 16; j++) {
    int idx = j * 256 + tid;
    int d = idx >> 5, sc = idx & 31;
    Vt[(((size_t)(b * 4 + kv)) * 128 + d) * 2048 + s0 + sc] = T[d * 33 + sc];
  }
}

// ---------------- causal GQA flash attention + sigmoid gate -> ag bf16 (B,S,H*D) ----
// R7 decomposition (512 blocks, waves own {2j, 2j+1, 63-2j, 62-2j}); single new
// change vs R7: V fragments are double-banked (vA/vB) and prefetched one half-tile
// ahead together with K, so the PV operand has a full half-tile of latency cover.
// Inner compute halfc() is pure-register (no loads inside).
__global__ __launch_bounds__(256) void attn(const bf16_t* __restrict__ Qr,
                                            const bf16_t* __restrict__ Kr,
                                            const bf16_t* __restrict__ Vt,
                                            const float* __restrict__ qkv,
                                            bf16_t* __restrict__ ag) {
  int bid = blockIdx.x;                 // 512 = 16h * 2b * 16jj
  int h = bid & 15, b = (bid >> 4) & 1, jj = bid >> 5;
  int kvh = h >> 2;
  int tid = threadIdx.x, lane = tid & 63, wv = tid >> 6;
  int lr = lane & 15, g = lane >> 4;
  int qg = (wv & 2) ? (63 - 2 * jj - (wv & 1)) : (2 * jj + (wv & 1));
  int qw = qg << 5;                     // wave q base (32 rows)
  int qrow0 = qw + lr, qrow1 = qrow0 + 16;
  int nh = qg + 1;                      // 32-wide kv half-tiles

  const bf16_t* Qg0 = Qr + (((size_t)(b * 16 + h)) * 2048 + qrow0) * 128;
  bf16x8 qf0[4], qf1[4];
#pragma unroll
  for (int ds = 0; ds < 4; ds++) {
    qf0[ds] = *(const bf16x8*)(Qg0 + ds * 32 + g * 8);
    qf1[ds] = *(const bf16x8*)(Qg0 + 16 * 128 + ds * 32 + g * 8);
  }
  const bf16_t* Kg = Kr + ((size_t)(b * 4 + kvh)) * 2048 * 128;
  const bf16_t* Vg = Vt + ((size_t)(b * 4 + kvh)) * 128 * 2048;

  f32x4 oa0[8], oa1[8];
#pragma unroll
  for (int i = 0; i < 8; i++)
#pragma unroll
    for (int r = 0; r < 4; r++) { oa0[i][r] = 0.f; oa1[i][r] = 0.f; }
  float mrun0 = -1e30f, mrun1 = -1e30f, lsp0 = 0.f, lsp1 = 0.f;

  int r0base = ((lr >> 2) << 3) + (lr & 3);       // pi(lr): A-row -> K-row map
  int kvlane = g << 3;

  bf16x8 kA[8], kB[8], vA[8], vB[8];

  auto loadK = [&](bf16x8 (&ka)[8], int kvb) {
    const bf16_t* kp = Kg + (size_t)(kvb + r0base) * 128 + g * 8;
#pragma unroll
    for (int ds = 0; ds < 4; ds++) {
      ka[ds]     = *(const bf16x8*)(kp + ds * 32);
      ka[4 + ds] = *(const bf16x8*)(kp + 4 * 128 + ds * 32);
    }
  };
  auto loadV = [&](bf16x8 (&vv)[8], int kvb) {
    const bf16_t* vp = Vg + (size_t)lr * 2048 + kvb + g * 8;
#pragma unroll
    for (int dt = 0; dt < 8; dt++)
      vv[dt] = *(const bf16x8*)(vp + (size_t)dt * 16 * 2048);
  };

  auto sm = [&](const f32x4& s0, const f32x4& s1, int qrow, int kvabs, bool dia,
                float& mrun, float& lsp, bf16x8& pb, f32x4 (&oac)[8]) {
    float tt[8];
#pragma unroll
    for (int r = 0; r < 4; r++) { tt[r] = s0[r]; tt[4 + r] = s1[r]; }
    if (dia) {
#pragma unroll
      for (int r = 0; r < 4; r++) {
        if (kvabs + r > qrow)     tt[r]     = -1e30f;
        if (kvabs + 4 + r > qrow) tt[4 + r] = -1e30f;
      }
    }
    float lm = fmaxf(fmaxf(fmaxf(tt[0], tt[1]), tt[2]),
                     fmaxf(fmaxf(tt[3], tt[4]), fmaxf(fmaxf(tt[5], tt[6]), tt[7])));
    if (__all(lm <= mrun + 8.f)) {      // defer-max common path: lane-local only
      float ps = 0.f;
#pragma unroll
      for (int i = 0; i < 8; i++) {
        float pv = __builtin_amdgcn_exp2f(tt[i] - mrun);
        pb[i] = (__bf16)pv; ps += pv;
      }
      lsp += ps;
    } else {                            // rare rescale path
      float pm = lm;
      pm = fmaxf(pm, __shfl_xor(pm, 16));
      pm = fmaxf(pm, __shfl_xor(pm, 32));
      float mnew = fmaxf(mrun, pm);
      float corr = __builtin_amdgcn_exp2f(mrun - mnew);
      float ps = 0.f;
#pragma unroll
      for (int i = 0; i < 8; i++) {
        float pv = __builtin_amdgcn_exp2f(tt[i] - mnew);
        pb[i] = (__bf16)pv; ps += pv;
      }
      lsp = lsp * corr + ps;
      mrun = mnew;
#pragma unroll
      for (int dt = 0; dt < 8; dt++)
#pragma unroll
        for (int r = 0; r < 4; r++) oac[dt][r] *= corr;
    }
  };

  auto halfc = [&](bf16x8 (&ka)[8], bf16x8 (&va)[8], int hh) {
    int kvb = hh << 5;
    f32x4 s00, s10, s01, s11;
#pragma unroll
    for (int r = 0; r < 4; r++) { s00[r] = 0.f; s10[r] = 0.f; s01[r] = 0.f; s11[r] = 0.f; }
    __builtin_amdgcn_s_setprio(1);
#pragma unroll
    for (int ds = 0; ds < 4; ds++) {
      s00 = __builtin_amdgcn_mfma_f32_16x16x32_bf16(ka[ds],     qf0[ds], s00, 0, 0, 0);
      s10 = __builtin_amdgcn_mfma_f32_16x16x32_bf16(ka[4 + ds], qf0[ds], s10, 0, 0, 0);
      s01 = __builtin_amdgcn_mfma_f32_16x16x32_bf16(ka[ds],     qf1[ds], s01, 0, 0, 0);
      s11 = __builtin_amdgcn_mfma_f32_16x16x32_bf16(ka[4 + ds], qf1[ds], s11, 0, 0, 0);
    }
    __builtin_amdgcn_s_setprio(0);
    int kvabs = kvb + kvlane;
    bool dia = (hh == qg);
    bf16x8 pb0, pb1;
    sm(s00, s10, qrow0, kvabs, dia, mrun0, lsp0, pb0, oa0);
    sm(s01, s11, qrow1, kvabs, dia, mrun1, lsp1, pb1, oa1);
    __builtin_amdgcn_s_setprio(1);
#pragma unroll
    for (int dt = 0; dt < 8; dt++) {
      oa0[dt] = __builtin_amdgcn_mfma_f32_16x16x32_bf16(va[dt], pb0, oa0[dt], 0, 0, 0);
      oa1[dt] = __builtin_amdgcn_mfma_f32_16x16x32_bf16(va[dt], pb1, oa1[dt], 0, 0, 0);
    }
    __builtin_amdgcn_s_setprio(0);
  };

  loadK(kA, 0);
  loadV(vA, 0);
  int hh = 0;
  for (; hh + 1 < nh; hh += 2) {
    loadK(kB, (hh + 1) << 5);
    loadV(vB, (hh + 1) << 5);
    halfc(kA, vA, hh);
    if (hh + 2 < nh) { loadK(kA, (hh + 2) << 5); loadV(vA, (hh + 2) << 5); }
    halfc(kB, vB, hh + 1);
  }
  if (hh < nh) halfc(kA, vA, hh);

  float ls0 = lsp0 + __shfl_xor(lsp0, 16);
  ls0 += __shfl_xor(ls0, 32);
  float ls1 = lsp1 + __shfl_xor(lsp1, 16);
  ls1 += __shfl_xor(ls1, 32);
  float invl0 = __builtin_amdgcn_rcpf(ls0);
  float invl1 = __builtin_amdgcn_rcpf(ls1);

  size_t ob0 = ((size_t)b * 2048 + qrow0) * 2048 + (h << 7);
  size_t gb0 = ((size_t)b * 2048 + qrow0) * 5120 + 2048 + (h << 7);
  size_t ob1 = ((size_t)b * 2048 + qrow1) * 2048 + (h << 7);
  size_t gb1 = ((size_t)b * 2048 + qrow1) * 5120 + 2048 + (h << 7);
#pragma unroll
  for (int dt = 0; dt < 8; dt++) {
    int d = dt * 16 + (g << 2);
    float4 gt0 = *(const float4*)(qkv + gb0 + d);
    float4 gt1 = *(const float4*)(qkv + gb1 + d);
    bf16x4v o0, o1;
    o0[0] = (__bf16)(oa0[dt][0] * invl0 * __builtin_amdgcn_rcpf(1.f + __builtin_amdgcn_exp2f(-gt0.x * LOG2E)));
    o0[1] = (__bf16)(oa0[dt][1] * invl0 * __builtin_amdgcn_rcpf(1.f + __builtin_amdgcn_exp2f(-gt0.y * LOG2E)));
    o0[2] = (__bf16)(oa0[dt][2] * invl0 * __builtin_amdgcn_rcpf(1.f + __builtin_amdgcn_exp2f(-gt0.z * LOG2E)));
    o0[3] = (__bf16)(oa0[dt][3] * invl0 * __builtin_amdgcn_rcpf(1.f + __builtin_amdgcn_exp2f(-gt0.w * LOG2E)));
    o1[0] = (__bf16)(oa1[dt][0] * invl1 * __builtin_amdgcn_rcpf(1.f + __builtin_amdgcn_exp2f(-gt1.x * LOG2E)));
    o1[1] = (__bf16)(oa1[dt][1] * invl1 * __builtin_amdgcn_rcpf(1.f + __builtin_amdgcn_exp2f(-gt1.y * LOG2E)));
    o1[2] = (__bf16)(oa1[dt][2] * invl1 * __builtin_amdgcn_rcpf(1.f + __builtin_amdgcn_exp2f(-gt1.z * LOG2E)));
    o1[3] = (__bf16)(oa1[dt][3] * invl1 * __builtin_amdgcn_rcpf(1.f + __builtin_amdgcn_exp2f(-gt1.w * LOG2E)));
    *(bf16x4v*)(ag + ob0 + d) = o0;
    *(bf16x4v*)(ag + ob1 + d) = o1;
  }
}

// ---------------- launch ----------------
extern "C" void kernel_launch(void* const* d_in, const int* in_sizes, int n_in,
                              void* d_out, int out_size, void* d_ws, size_t ws_size,
                              hipStream_t stream) {
  const float* x    = (const float*)d_in[0];
  const float* wqkv = (const float*)d_in[1];
  const float* wo   = (const float*)d_in[2];
  const float* qnw  = (const float*)d_in[3];
  const float* qnb  = (const float*)d_in[4];
  const float* knw  = (const float*)d_in[5];
  const float* knb  = (const float*)d_in[6];
  float* out = (float*)d_out;

  char* p = (char*)d_ws;
  bf16_t* xb  = (bf16_t*)p;           // 16 MB, reused as ag after GEMM1
  bf16_t* ag  = xb;
  p += (size_t)16777216;
  bf16_t* wqb = (bf16_t*)p;           // 20 MB, reused as Qr after GEMM1
  bf16_t* Qr  = wqb;
  p += (size_t)20971520;
  bf16_t* wob = (bf16_t*)p; p += (size_t)8388608;
  float*  qkv = (float*)p;  p += (size_t)83886080;
  bf16_t* Kr  = (bf16_t*)p; p += (size_t)4194304;
  bf16_t* Vt  = (bf16_t*)p; p += (size_t)4194304;
  float* cosT = (float*)p;  p += (size_t)524288;
  float* sinT = (float*)p;  p += (size_t)524288;

  cvt_f32_bf16<<<8192, 256, 0, stream>>>(x, xb, 2097152);
  cvt_f32_bf16<<<10240, 256, 0, stream>>>(wqkv, wqb, 2621440);
  cvt_f32_bf16<<<4096, 256, 0, stream>>>(wo, wob, 1048576);
  rope_tables<<<512, 256, 0, stream>>>(cosT, sinT);

  // qkv = x @ w_qkv^T   (4096 x 5120 x K=2048): BM=256, BN=320 -> 256 blocks
  gemm8p<8, 5><<<256, 512, 0, stream>>>(xb, wqb, qkv, 4096, 5120, 2048);

  ln_rope<<<4096, 256, 0, stream>>>(qkv, qnw, qnb, knw, knb, cosT, sinT, Qr, Kr);
  vtrans<<<512, 256, 0, stream>>>(qkv, Vt);

  attn<<<512, 256, 0, stream>>>(Qr, Kr, Vt, qkv, ag);

  // out = ag @ w_o^T    (4096 x 2048 x K=2048): BM=128, BN=256 -> 256 blocks
  gemm8p<4, 4><<<256, 512, 0, stream>>>(ag, wob, out, 4096, 2048, 2048);
}

// Round 10
// 272.346 us; speedup vs baseline: 1.2667x; 1.2368x over previous
//
#include <hip/hip_runtime.h>
#include <hip/hip_bf16.h>

typedef __bf16 bf16_t;
typedef __bf16 bf16x2 __attribute__((ext_vector_type(2)));
typedef __bf16 bf16x4v __attribute__((ext_vector_type(4)));
typedef __bf16 bf16x8 __attribute__((ext_vector_type(8)));
typedef float f32x4 __attribute__((ext_vector_type(4)));

#define LOG2E 1.4426950408889634f
// (1/sqrt(128)) * log2(e), folded into Q at ln_rope time
#define QSCALE (0.08838834764831843f * 1.4426950408889634f)

// ---------------- fp32 -> bf16 conversion ----------------
__global__ __launch_bounds__(256) void cvt_f32_bf16(const float* __restrict__ in,
                                                    bf16_t* __restrict__ out, int n4) {
  int i = blockIdx.x * 256 + threadIdx.x;
  if (i < n4) {
    float4 v = ((const float4*)in)[i];
    bf16x4v o;
    o[0] = (__bf16)v.x; o[1] = (__bf16)v.y; o[2] = (__bf16)v.z; o[3] = (__bf16)v.w;
    *(bf16x4v*)(out + (size_t)i * 4) = o;
  }
}

// ---------------- RoPE cos/sin tables: [S=2048][64] ----------------
__global__ __launch_bounds__(256) void rope_tables(float* __restrict__ cosT,
                                                   float* __restrict__ sinT) {
  int idx = blockIdx.x * 256 + threadIdx.x;   // 2048*64 = 131072
  int s = idx >> 6, i = idx & 63;
  float inv = __builtin_amdgcn_exp2f(-(float)i * (19.931568569324174f / 64.0f));
  float f = (float)s * inv;
  cosT[idx] = cosf(f);
  sinT[idx] = sinf(f);
}

// ---------------- bf16 NT GEMM, phase-scheduled ----------------
template<int MI, int NI>
__global__ __launch_bounds__(512) void gemm8p(const bf16_t* __restrict__ A,
                                              const bf16_t* __restrict__ B,
                                              float* __restrict__ C,
                                              int M, int N, int K) {
  constexpr int BM = MI * 32;
  constexpr int BN = NI * 64;
  constexpr int NA = BM / 64;            // A stage insts per K-tile
  constexpr int NB = BN / 64;            // B stage insts per K-tile
  constexpr int ST = NA + NB;
  constexpr int PH = MI / 2;             // phases per K-tile (4 or 2)
  constexpr int stBase = ST / PH;
  constexpr int stFirst = ST - stBase * (PH - 1);   // == 3 for both configs
  static_assert(stFirst == 3, "vmcnt literal assumes 3 first-phase stages");

  __shared__ bf16_t LA[2][BM * 64];
  __shared__ bf16_t LB[2][BN * 64];

  int nb = N / BN;
  int cpx = gridDim.x >> 3;              // grid divisible by 8
  int bid = blockIdx.x;
  int swz = (bid & 7) * cpx + (bid >> 3);
  int bm = swz / nb, bn = swz % nb;
  int m0 = bm * BM, n0 = bn * BN;
  int tid = threadIdx.x, lane = tid & 63, wv = tid >> 6;
  int wr = wv >> 2, wc = wv & 3, lr = lane & 15, g = lane >> 4;
  int T = K >> 6;

  auto stageI = [&](int kt, int bi, int s) {
    int k0 = kt << 6;
    if (s < NA) {
      int c = s * 512 + tid;
      int row = c >> 3, lc = (c & 7) ^ (row & 7);
      __builtin_amdgcn_global_load_lds(
          (const __attribute__((address_space(1))) void*)(A + (size_t)(m0 + row) * K + k0 + lc * 8),
          (__attribute__((address_space(3))) void*)&LA[bi][(s * 512 + wv * 64) * 8], 16, 0, 0);
    } else {
      int c = (s - NA) * 512 + tid;
      int row = c >> 3, lc = (c & 7) ^ (row & 7);
      __builtin_amdgcn_global_load_lds(
          (const __attribute__((address_space(1))) void*)(B + (size_t)(n0 + row) * K + k0 + lc * 8),
          (__attribute__((address_space(3))) void*)&LB[bi][((s - NA) * 512 + wv * 64) * 8], 16, 0, 0);
    }
  };

  f32x4 acc[MI][NI];
#pragma unroll
  for (int i = 0; i < MI; i++)
#pragma unroll
    for (int j = 0; j < NI; j++)
#pragma unroll
      for (int r = 0; r < 4; r++) acc[i][j][r] = 0.f;

#pragma unroll
  for (int s = 0; s < ST; s++) stageI(0, 0, s);

  int ofk0 = ((0 + g) ^ (lr & 7)) << 3;
  int ofk1 = ((4 + g) ^ (lr & 7)) << 3;
  int offA = (wr * (MI * 16) + lr) * 64;
  int offB = (wc * (NI * 16) + lr) * 64;

  for (int t = 0; t < T; t++) {
    int bi = t & 1, bo = bi ^ 1;
    const bf16_t* la = LA[bi];
    const bf16_t* lb = LB[bi];
    bool pre = (t + 1 < T);
    bf16x8 bq[NI];
#pragma unroll
    for (int ph = 0; ph < PH; ph++) {
      const int s0 = (ph == 0) ? 0 : stFirst + (ph - 1) * stBase;
      const int sc = (ph == 0) ? stFirst : stBase;
      if (pre) {
#pragma unroll
        for (int s = s0; s < s0 + sc; s++) stageI(t + 1, bo, s);
      }
      if (ph == 0) {
        if (pre) asm volatile("s_waitcnt vmcnt(3)" ::: "memory");
        else     asm volatile("s_waitcnt vmcnt(0)" ::: "memory");
        __builtin_amdgcn_s_barrier();
        asm volatile("" ::: "memory");
      }
      const int ks = (PH == 4) ? (ph >> 1) : ph;
      const int q  = (PH == 4) ? (ph & 1) : 0;
      const bool rb = (PH == 2) || ((ph & 1) == 0);
      const int ofk = ks ? ofk1 : ofk0;
      bf16x8 af[4];
#pragma unroll
      for (int i = 0; i < 4; i++)
        af[i] = *(const bf16x8*)&la[offA + (q * 4 + i) * 1024 + ofk];
      if (rb) {
#pragma unroll
        for (int ni = 0; ni < NI; ni++)
          bq[ni] = *(const bf16x8*)&lb[offB + ni * 1024 + ofk];
      }
      if (ph != 0) {
        asm volatile("" ::: "memory");
        __builtin_amdgcn_s_barrier();
        asm volatile("" ::: "memory");
      }
      __builtin_amdgcn_s_setprio(1);
#pragma unroll
      for (int i = 0; i < 4; i++)
#pragma unroll
        for (int ni = 0; ni < NI; ni++)
          acc[q * 4 + i][ni] =
              __builtin_amdgcn_mfma_f32_16x16x32_bf16(af[i], bq[ni], acc[q * 4 + i][ni], 0, 0, 0);
      __builtin_amdgcn_s_setprio(0);
      asm volatile("s_waitcnt lgkmcnt(0)" ::: "memory");
      __builtin_amdgcn_s_barrier();
      asm volatile("" ::: "memory");
    }
  }

#pragma unroll
  for (int mi = 0; mi < MI; mi++)
#pragma unroll
    for (int ni = 0; ni < NI; ni++) {
      int m = m0 + wr * (MI * 16) + mi * 16 + g * 4;
      int n = n0 + wc * (NI * 16) + ni * 16 + lr;
#pragma unroll
      for (int r = 0; r < 4; r++) C[(size_t)(m + r) * N + n] = acc[mi][ni][r];
    }
}

// ---------------- fused per-head LayerNorm + RoPE -> bf16 Q(B,H,S,D), K(B,KV,S,D) ----
__global__ __launch_bounds__(256) void ln_rope(const float* __restrict__ qkv,
                                               const float* __restrict__ qw, const float* __restrict__ qb,
                                               const float* __restrict__ kw, const float* __restrict__ kb,
                                               const float* __restrict__ cosT, const float* __restrict__ sinT,
                                               bf16_t* __restrict__ Qr, bf16_t* __restrict__ Kr) {
  int row = blockIdx.x;              // b*2048 + s
  int b = row >> 11, s = row & 2047;
  int lane = threadIdx.x & 63, wv = threadIdx.x >> 6;
  float c = cosT[(s << 6) + lane], sn = sinT[(s << 6) + lane];
  const float* base = qkv + (size_t)row * 5120;
#pragma unroll
  for (int i = 0; i < 5; i++) {
    int head = wv * 5 + i;           // 0..15 = q heads, 16..19 = k heads
    bool isq = head < 16;
    int off = isq ? (head << 7) : (4096 + ((head - 16) << 7));
    float2 x = *(const float2*)(base + off + (lane << 1));
    float sum = x.x + x.y;
#pragma unroll
    for (int m = 1; m < 64; m <<= 1) sum += __shfl_xor(sum, m);
    float mu = sum * 0.0078125f;
    float x0 = x.x - mu, x1 = x.y - mu;
    float vs = x0 * x0 + x1 * x1;
#pragma unroll
    for (int m = 1; m < 64; m <<= 1) vs += __shfl_xor(vs, m);
    float rs = rsqrtf(vs * 0.0078125f + 1e-6f);
    const float* w = isq ? qw : kw;
    const float* bb = isq ? qb : kb;
    float y0 = x0 * rs * w[lane << 1] + bb[lane << 1];
    float y1 = x1 * rs * w[(lane << 1) + 1] + bb[(lane << 1) + 1];
    float o0 = y0 * c - y1 * sn;
    float o1 = y0 * sn + y1 * c;
    if (isq) { o0 *= QSCALE; o1 *= QSCALE; }
    bf16x2 ov; ov[0] = (__bf16)o0; ov[1] = (__bf16)o1;
    size_t dst = isq ? ((((size_t)(b * 16 + head)) * 2048 + s) * 128 + (lane << 1))
                     : ((((size_t)(b * 4 + (head - 16))) * 2048 + s) * 128 + (lane << 1));
    *(bf16x2*)((isq ? Qr : Kr) + dst) = ov;
  }
}

// ---------------- V transpose: qkv v-slice (B,S,KV,D) -> Vt (B,KV,D,S) bf16 -------
__global__ __launch_bounds__(256) void vtrans(const float* __restrict__ qkv,
                                              bf16_t* __restrict__ Vt) {
  int bid = blockIdx.x;              // ((b*4+kv)*64 + sb)
  int sb = bid & 63, kv = (bid >> 6) & 3, b = bid >> 8;
  int s0 = sb << 5;
  __shared__ bf16_t T[128 * 33];
  int tid = threadIdx.x;
#pragma unroll
  for (int i = 0; i < 16; i++) {
    int idx = i * 256 + tid;         // 0..4095
    int r = idx >> 7, d = idx & 127;
    float v = qkv[((size_t)(b * 2048 + s0 + r)) * 5120 + 4608 + (kv << 7) + d];
    T[d * 33 + r] = (__bf16)v;
  }
  __syncthreads();
#pragma unroll
  for (int j = 0; j < 16; j++) {
    int idx = j * 256 + tid;
    int d = idx >> 5, sc = idx & 31;
    Vt[(((size_t)(b * 4 + kv)) * 128 + d) * 2048 + s0 + sc] = T[d * 33 + sc];
  }
}

// ---------------- causal GQA flash attention + sigmoid gate -> ag bf16 (B,S,H*D) ----
// Shared-LDS structure: block = (pair pr, h, b), 4 waves x 16 q-rows = 64 q-rows,
// processed in two sequential phases (q-block pr, then 31-pr) -> 66 equal kv-tiles
// per block. K/V staged in LDS (32 KB double-buffered) via global_load_lds with
// both-sides XOR swizzle; counted vmcnt(4); vmcnt -> barrier -> reads ordering
// (R7-proven). Lane-local defer-max softmax unchanged (verified since R4).
__global__ __launch_bounds__(256, 3) void attn(const bf16_t* __restrict__ Qr,
                                               const bf16_t* __restrict__ Kr,
                                               const bf16_t* __restrict__ Vt,
                                               const float* __restrict__ qkv,
                                               bf16_t* __restrict__ ag) {
  __shared__ bf16_t Ks[2][32 * 128];   // 16 KB: K tiles (rows kv, cols d), XOR row&15
  __shared__ bf16_t Vs[2][128 * 32];   // 16 KB: V^T tiles (rows d, cols kv), XOR (d>>1)&3
  int bid = blockIdx.x;                // 512 = 16 pr * (16 h * 2 b)
  int hb = bid & 31;
  int h = hb & 15, b = hb >> 4;
  int pr = bid >> 5;                   // 0..15
  int kvh = h >> 2;
  int tid = threadIdx.x, lane = tid & 63, wv = tid >> 6;
  int lr = lane & 15, g = lane >> 4;
  int r0base = ((lr >> 2) << 3) + (lr & 3);   // pi(lr): A-row -> K-row map

  const bf16_t* Kg = Kr + ((size_t)(b * 4 + kvh)) * 2048 * 128;
  const bf16_t* Vg = Vt + ((size_t)(b * 4 + kvh)) * 128 * 2048;

  auto stage = [&](int buf, int kv0) {
#pragma unroll
    for (int i = 0; i < 2; i++) {      // K: 8 KB, 512 chunks of 16 B
      int c = i * 256 + tid;
      int row = c >> 4, lc = (c & 15) ^ (row & 15);
      __builtin_amdgcn_global_load_lds(
          (const __attribute__((address_space(1))) void*)(Kg + (size_t)(kv0 + row) * 128 + lc * 8),
          (__attribute__((address_space(3))) void*)&Ks[buf][c * 8], 16, 0, 0);
    }
#pragma unroll
    for (int i = 0; i < 2; i++) {      // V: 8 KB
      int c = i * 256 + tid;
      int d = c >> 2, cv = (c & 3) ^ ((d >> 1) & 3);
      __builtin_amdgcn_global_load_lds(
          (const __attribute__((address_space(1))) void*)(Vg + (size_t)d * 2048 + kv0 + cv * 8),
          (__attribute__((address_space(3))) void*)&Vs[buf][c * 8], 16, 0, 0);
    }
  };

  auto sm = [&](const f32x4& s0, const f32x4& s1, int qrow, int kvabs, bool dia,
                float& mrun, float& lsp, bf16x8& pb, f32x4 (&oac)[8]) {
    float tt[8];
#pragma unroll
    for (int r = 0; r < 4; r++) { tt[r] = s0[r]; tt[4 + r] = s1[r]; }
    if (dia) {
#pragma unroll
      for (int r = 0; r < 4; r++) {
        if (kvabs + r > qrow)     tt[r]     = -1e30f;
        if (kvabs + 4 + r > qrow) tt[4 + r] = -1e30f;
      }
    }
    float lm = fmaxf(fmaxf(fmaxf(tt[0], tt[1]), tt[2]),
                     fmaxf(fmaxf(tt[3], tt[4]), fmaxf(fmaxf(tt[5], tt[6]), tt[7])));
    if (__all(lm <= mrun + 8.f)) {      // defer-max common path: lane-local only
      float ps = 0.f;
#pragma unroll
      for (int i = 0; i < 8; i++) {
        float pv = __builtin_amdgcn_exp2f(tt[i] - mrun);
        pb[i] = (__bf16)pv; ps += pv;
      }
      lsp += ps;
    } else {                            // rare rescale path
      float pm = lm;
      pm = fmaxf(pm, __shfl_xor(pm, 16));
      pm = fmaxf(pm, __shfl_xor(pm, 32));
      float mnew = fmaxf(mrun, pm);
      float corr = __builtin_amdgcn_exp2f(mrun - mnew);
      float ps = 0.f;
#pragma unroll
      for (int i = 0; i < 8; i++) {
        float pv = __builtin_amdgcn_exp2f(tt[i] - mnew);
        pb[i] = (__bf16)pv; ps += pv;
      }
      lsp = lsp * corr + ps;
      mrun = mnew;
#pragma unroll
      for (int dt = 0; dt < 8; dt++)
#pragma unroll
        for (int r = 0; r < 4; r++) oac[dt][r] *= corr;
    }
  };

  for (int phase = 0; phase < 2; phase++) {
    int qb = phase ? (31 - pr) : pr;   // 64-row q-block index
    int qw0 = qb << 6;
    int qw = qw0 + (wv << 4);          // wave q base (16 rows)
    int qrow = qw + lr;
    int qmax = qw + 15;
    int nt = (qb + 1) << 1;            // 32-wide kv tiles

    const bf16_t* Qg = Qr + (((size_t)(b * 16 + h)) * 2048 + qrow) * 128;
    bf16x8 qf[4];
#pragma unroll
    for (int ds = 0; ds < 4; ds++) qf[ds] = *(const bf16x8*)(Qg + ds * 32 + g * 8);

    f32x4 oa[8];
#pragma unroll
    for (int i = 0; i < 8; i++)
#pragma unroll
      for (int r = 0; r < 4; r++) oa[i][r] = 0.f;
    float mrun = -1e30f, lsp = 0.f;

    stage(0, 0);
    for (int t = 0; t < nt; t++) {
      int cur = t & 1;
      if (t + 1 < nt) {
        stage(cur ^ 1, (t + 1) << 5);
        asm volatile("s_waitcnt vmcnt(4)" ::: "memory");   // tile t landed; t+1 in flight
      } else {
        asm volatile("s_waitcnt vmcnt(0)" ::: "memory");
      }
      __builtin_amdgcn_s_barrier();
      asm volatile("" ::: "memory");
      int kvb = t << 5;
      if (kvb <= qmax) {
        const bf16_t* kb = Ks[cur];
        const bf16_t* vb = Vs[cur];
        int ra = r0base, rb2 = r0base + 4;
        bf16x8 a0[4], a1[4];
#pragma unroll
        for (int ds = 0; ds < 4; ds++) {
          a0[ds] = *(const bf16x8*)&kb[ra * 128 + (((ds * 4 + g) ^ (ra & 15)) << 3)];
          a1[ds] = *(const bf16x8*)&kb[rb2 * 128 + (((ds * 4 + g) ^ (rb2 & 15)) << 3)];
        }
        f32x4 s0, s1;
#pragma unroll
        for (int r = 0; r < 4; r++) { s0[r] = 0.f; s1[r] = 0.f; }
        __builtin_amdgcn_s_setprio(1);
#pragma unroll
        for (int ds = 0; ds < 4; ds++) {
          s0 = __builtin_amdgcn_mfma_f32_16x16x32_bf16(a0[ds], qf[ds], s0, 0, 0, 0);
          s1 = __builtin_amdgcn_mfma_f32_16x16x32_bf16(a1[ds], qf[ds], s1, 0, 0, 0);
        }
        __builtin_amdgcn_s_setprio(0);
        int kvabs = kvb + (g << 3);
        bool dia = (kvb + 31 > qw);
        bf16x8 pb;
        sm(s0, s1, qrow, kvabs, dia, mrun, lsp, pb, oa);
        __builtin_amdgcn_s_setprio(1);
#pragma unroll
        for (int dt = 0; dt < 8; dt++) {
          int d = dt * 16 + lr;
          bf16x8 va = *(const bf16x8*)&vb[d * 32 + ((g ^ ((d >> 1) & 3)) << 3)];
          oa[dt] = __builtin_amdgcn_mfma_f32_16x16x32_bf16(va, pb, oa[dt], 0, 0, 0);
        }
        __builtin_amdgcn_s_setprio(0);
      }
      asm volatile("s_waitcnt lgkmcnt(0)" ::: "memory");   // my ds_reads done before recycle
      __builtin_amdgcn_s_barrier();
      asm volatile("" ::: "memory");
    }

    float ls = lsp + __shfl_xor(lsp, 16);
    ls += __shfl_xor(ls, 32);
    float invl = __builtin_amdgcn_rcpf(ls);

    size_t ob = ((size_t)b * 2048 + qrow) * 2048 + (h << 7);
    size_t gb = ((size_t)b * 2048 + qrow) * 5120 + 2048 + (h << 7);
#pragma unroll
    for (int dt = 0; dt < 8; dt++) {
      int d = dt * 16 + (g << 2);
      float4 gt = *(const float4*)(qkv + gb + d);
      bf16x4v o;
      o[0] = (__bf16)(oa[dt][0] * invl * __builtin_amdgcn_rcpf(1.f + __builtin_amdgcn_exp2f(-gt.x * LOG2E)));
      o[1] = (__bf16)(oa[dt][1] * invl * __builtin_amdgcn_rcpf(1.f + __builtin_amdgcn_exp2f(-gt.y * LOG2E)));
      o[2] = (__bf16)(oa[dt][2] * invl * __builtin_amdgcn_rcpf(1.f + __builtin_amdgcn_exp2f(-gt.z * LOG2E)));
      o[3] = (__bf16)(oa[dt][3] * invl * __builtin_amdgcn_rcpf(1.f + __builtin_amdgcn_exp2f(-gt.w * LOG2E)));
      *(bf16x4v*)(ag + ob + d) = o;
    }
  }
}

// ---------------- launch ----------------
extern "C" void kernel_launch(void* const* d_in, const int* in_sizes, int n_in,
                              void* d_out, int out_size, void* d_ws, size_t ws_size,
                              hipStream_t stream) {
  const float* x    = (const float*)d_in[0];
  const float* wqkv = (const float*)d_in[1];
  const float* wo   = (const float*)d_in[2];
  const float* qnw  = (const float*)d_in[3];
  const float* qnb  = (const float*)d_in[4];
  const float* knw  = (const float*)d_in[5];
  const float* knb  = (const float*)d_in[6];
  float* out = (float*)d_out;

  char* p = (char*)d_ws;
  bf16_t* xb  = (bf16_t*)p;           // 16 MB, reused as ag after GEMM1
  bf16_t* ag  = xb;
  p += (size_t)16777216;
  bf16_t* wqb = (bf16_t*)p;           // 20 MB, reused as Qr after GEMM1
  bf16_t* Qr  = wqb;
  p += (size_t)20971520;
  bf16_t* wob = (bf16_t*)p; p += (size_t)8388608;
  float*  qkv = (float*)p;  p += (size_t)83886080;
  bf16_t* Kr  = (bf16_t*)p; p += (size_t)4194304;
  bf16_t* Vt  = (bf16_t*)p; p += (size_t)4194304;
  float* cosT = (float*)p;  p += (size_t)524288;
  float* sinT = (float*)p;  p += (size_t)524288;

  cvt_f32_bf16<<<8192, 256, 0, stream>>>(x, xb, 2097152);
  cvt_f32_bf16<<<10240, 256, 0, stream>>>(wqkv, wqb, 2621440);
  cvt_f32_bf16<<<4096, 256, 0, stream>>>(wo, wob, 1048576);
  rope_tables<<<512, 256, 0, stream>>>(cosT, sinT);

  // qkv = x @ w_qkv^T   (4096 x 5120 x K=2048): BM=256, BN=320 -> 256 blocks
  gemm8p<8, 5><<<256, 512, 0, stream>>>(xb, wqb, qkv, 4096, 5120, 2048);

  ln_rope<<<4096, 256, 0, stream>>>(qkv, qnw, qnb, knw, knb, cosT, sinT, Qr, Kr);
  vtrans<<<512, 256, 0, stream>>>(qkv, Vt);

  attn<<<512, 256, 0, stream>>>(Qr, Kr, Vt, qkv, ag);

  // out = ag @ w_o^T    (4096 x 2048 x K=2048): BM=128, BN=256 -> 256 blocks
  gemm8p<4, 4><<<256, 512, 0, stream>>>(ag, wob, out, 4096, 2048, 2048);
}

// Round 11
// 255.000 us; speedup vs baseline: 1.3528x; 1.0680x over previous
//
#include <hip/hip_runtime.h>
#include <hip/hip_bf16.h>

typedef __bf16 bf16_t;
typedef __bf16 bf16x2 __attribute__((ext_vector_type(2)));
typedef __bf16 bf16x4v __attribute__((ext_vector_type(4)));
typedef __bf16 bf16x8 __attribute__((ext_vector_type(8)));
typedef float f32x4 __attribute__((ext_vector_type(4)));

#define LOG2E 1.4426950408889634f
// (1/sqrt(128)) * log2(e), folded into Q at ln_rope time
#define QSCALE (0.08838834764831843f * 1.4426950408889634f)

// ---------------- fp32 -> bf16 conversion ----------------
__global__ __launch_bounds__(256) void cvt_f32_bf16(const float* __restrict__ in,
                                                    bf16_t* __restrict__ out, int n4) {
  int i = blockIdx.x * 256 + threadIdx.x;
  if (i < n4) {
    float4 v = ((const float4*)in)[i];
    bf16x4v o;
    o[0] = (__bf16)v.x; o[1] = (__bf16)v.y; o[2] = (__bf16)v.z; o[3] = (__bf16)v.w;
    *(bf16x4v*)(out + (size_t)i * 4) = o;
  }
}

// ---------------- RoPE cos/sin tables: [S=2048][64] ----------------
__global__ __launch_bounds__(256) void rope_tables(float* __restrict__ cosT,
                                                   float* __restrict__ sinT) {
  int idx = blockIdx.x * 256 + threadIdx.x;   // 2048*64 = 131072
  int s = idx >> 6, i = idx & 63;
  float inv = __builtin_amdgcn_exp2f(-(float)i * (19.931568569324174f / 64.0f));
  float f = (float)s * inv;
  cosT[idx] = cosf(f);
  sinT[idx] = sinf(f);
}

// ---------------- bf16 NT GEMM, phase-scheduled, full-tile prefetch ----------------
// C[m,n] = sum_k A[m,k]*B[n,k], fp32 out. 512 threads = 8 waves (2M x 4N).
// BM = MI*32, BN = NI*64; per-wave output (MI*16) x (NI*16). BK=64, double-buffered.
// ALL ST stage insts for tile t+1 are issued at phase 0 of tile t (full-tile
// lookahead ~4 phases of latency cover; buffer bo's readers finished at end of
// tile t-2, sealed by the tile-boundary barrier). vmcnt(ST) -> barrier -> reads.
template<int MI, int NI>
__global__ __launch_bounds__(512) void gemm8p(const bf16_t* __restrict__ A,
                                              const bf16_t* __restrict__ B,
                                              float* __restrict__ C,
                                              int M, int N, int K) {
  constexpr int BM = MI * 32;
  constexpr int BN = NI * 64;
  constexpr int NA = BM / 64;            // A stage insts per K-tile
  constexpr int NB = BN / 64;            // B stage insts per K-tile
  constexpr int ST = NA + NB;            // 9 for <8,5>, 6 for <4,4>
  constexpr int PH = MI / 2;             // phases per K-tile (4 or 2)

  __shared__ bf16_t LA[2][BM * 64];
  __shared__ bf16_t LB[2][BN * 64];

  int nb = N / BN;
  int cpx = gridDim.x >> 3;              // grid divisible by 8
  int bid = blockIdx.x;
  int swz = (bid & 7) * cpx + (bid >> 3);
  int bm = swz / nb, bn = swz % nb;
  int m0 = bm * BM, n0 = bn * BN;
  int tid = threadIdx.x, lane = tid & 63, wv = tid >> 6;
  int wr = wv >> 2, wc = wv & 3, lr = lane & 15, g = lane >> 4;
  int T = K >> 6;

  auto stageI = [&](int kt, int bi, int s) {
    int k0 = kt << 6;
    if (s < NA) {
      int c = s * 512 + tid;
      int row = c >> 3, lc = (c & 7) ^ (row & 7);
      __builtin_amdgcn_global_load_lds(
          (const __attribute__((address_space(1))) void*)(A + (size_t)(m0 + row) * K + k0 + lc * 8),
          (__attribute__((address_space(3))) void*)&LA[bi][(s * 512 + wv * 64) * 8], 16, 0, 0);
    } else {
      int c = (s - NA) * 512 + tid;
      int row = c >> 3, lc = (c & 7) ^ (row & 7);
      __builtin_amdgcn_global_load_lds(
          (const __attribute__((address_space(1))) void*)(B + (size_t)(n0 + row) * K + k0 + lc * 8),
          (__attribute__((address_space(3))) void*)&LB[bi][((s - NA) * 512 + wv * 64) * 8], 16, 0, 0);
    }
  };

  f32x4 acc[MI][NI];
#pragma unroll
  for (int i = 0; i < MI; i++)
#pragma unroll
    for (int j = 0; j < NI; j++)
#pragma unroll
      for (int r = 0; r < 4; r++) acc[i][j][r] = 0.f;

  // prologue: stage K-tile 0 into buf 0
#pragma unroll
  for (int s = 0; s < ST; s++) stageI(0, 0, s);

  int ofk0 = ((0 + g) ^ (lr & 7)) << 3;
  int ofk1 = ((4 + g) ^ (lr & 7)) << 3;
  int offA = (wr * (MI * 16) + lr) * 64;
  int offB = (wc * (NI * 16) + lr) * 64;

  for (int t = 0; t < T; t++) {
    int bi = t & 1, bo = bi ^ 1;
    const bf16_t* la = LA[bi];
    const bf16_t* lb = LB[bi];
    bool pre = (t + 1 < T);
    // issue the ENTIRE next tile's staging up front (max lookahead), then wait
    // for tile t to have fully landed (ST of t+1 may remain in flight).
    if (pre) {
#pragma unroll
      for (int s = 0; s < ST; s++) stageI(t + 1, bo, s);
      if constexpr (ST == 9) asm volatile("s_waitcnt vmcnt(9)" ::: "memory");
      else                   asm volatile("s_waitcnt vmcnt(6)" ::: "memory");
    } else {
      asm volatile("s_waitcnt vmcnt(0)" ::: "memory");
    }
    __builtin_amdgcn_s_barrier();
    asm volatile("" ::: "memory");       // no load hoisting above the barrier
    bf16x8 bq[NI];
#pragma unroll
    for (int ph = 0; ph < PH; ph++) {
      const int ks = (PH == 4) ? (ph >> 1) : ph;
      const int q  = (PH == 4) ? (ph & 1) : 0;
      const bool rb = (PH == 2) || ((ph & 1) == 0);
      const int ofk = ks ? ofk1 : ofk0;
      bf16x8 af[4];
#pragma unroll
      for (int i = 0; i < 4; i++)
        af[i] = *(const bf16x8*)&la[offA + (q * 4 + i) * 1024 + ofk];
      if (rb) {
#pragma unroll
        for (int ni = 0; ni < NI; ni++)
          bq[ni] = *(const bf16x8*)&lb[offB + ni * 1024 + ofk];
      }
      if (ph != 0) {
        asm volatile("" ::: "memory");
        __builtin_amdgcn_s_barrier();    // phase separation (role-split lockstep)
        asm volatile("" ::: "memory");
      }
      __builtin_amdgcn_s_setprio(1);
#pragma unroll
      for (int i = 0; i < 4; i++)
#pragma unroll
        for (int ni = 0; ni < NI; ni++)
          acc[q * 4 + i][ni] =
              __builtin_amdgcn_mfma_f32_16x16x32_bf16(af[i], bq[ni], acc[q * 4 + i][ni], 0, 0, 0);
      __builtin_amdgcn_s_setprio(0);
      asm volatile("s_waitcnt lgkmcnt(0)" ::: "memory");  // my ds_reads done before recycle
      __builtin_amdgcn_s_barrier();
      asm volatile("" ::: "memory");
    }
  }

#pragma unroll
  for (int mi = 0; mi < MI; mi++)
#pragma unroll
    for (int ni = 0; ni < NI; ni++) {
      int m = m0 + wr * (MI * 16) + mi * 16 + g * 4;
      int n = n0 + wc * (NI * 16) + ni * 16 + lr;
#pragma unroll
      for (int r = 0; r < 4; r++) C[(size_t)(m + r) * N + n] = acc[mi][ni][r];
    }
}

// ---------------- fused per-head LayerNorm + RoPE -> bf16 Q(B,H,S,D), K(B,KV,S,D) ----
__global__ __launch_bounds__(256) void ln_rope(const float* __restrict__ qkv,
                                               const float* __restrict__ qw, const float* __restrict__ qb,
                                               const float* __restrict__ kw, const float* __restrict__ kb,
                                               const float* __restrict__ cosT, const float* __restrict__ sinT,
                                               bf16_t* __restrict__ Qr, bf16_t* __restrict__ Kr) {
  int row = blockIdx.x;              // b*2048 + s
  int b = row >> 11, s = row & 2047;
  int lane = threadIdx.x & 63, wv = threadIdx.x >> 6;
  float c = cosT[(s << 6) + lane], sn = sinT[(s << 6) + lane];
  const float* base = qkv + (size_t)row * 5120;
#pragma unroll
  for (int i = 0; i < 5; i++) {
    int head = wv * 5 + i;           // 0..15 = q heads, 16..19 = k heads
    bool isq = head < 16;
    int off = isq ? (head << 7) : (4096 + ((head - 16) << 7));
    float2 x = *(const float2*)(base + off + (lane << 1));
    float sum = x.x + x.y;
#pragma unroll
    for (int m = 1; m < 64; m <<= 1) sum += __shfl_xor(sum, m);
    float mu = sum * 0.0078125f;
    float x0 = x.x - mu, x1 = x.y - mu;
    float vs = x0 * x0 + x1 * x1;
#pragma unroll
    for (int m = 1; m < 64; m <<= 1) vs += __shfl_xor(vs, m);
    float rs = rsqrtf(vs * 0.0078125f + 1e-6f);
    const float* w = isq ? qw : kw;
    const float* bb = isq ? qb : kb;
    float y0 = x0 * rs * w[lane << 1] + bb[lane << 1];
    float y1 = x1 * rs * w[(lane << 1) + 1] + bb[(lane << 1) + 1];
    float o0 = y0 * c - y1 * sn;
    float o1 = y0 * sn + y1 * c;
    if (isq) { o0 *= QSCALE; o1 *= QSCALE; }
    bf16x2 ov; ov[0] = (__bf16)o0; ov[1] = (__bf16)o1;
    size_t dst = isq ? ((((size_t)(b * 16 + head)) * 2048 + s) * 128 + (lane << 1))
                     : ((((size_t)(b * 4 + (head - 16))) * 2048 + s) * 128 + (lane << 1));
    *(bf16x2*)((isq ? Qr : Kr) + dst) = ov;
  }
}

// ---------------- V transpose: qkv v-slice (B,S,KV,D) -> Vt (B,KV,D,S) bf16 -------
__global__ __launch_bounds__(256) void vtrans(const float* __restrict__ qkv,
                                              bf16_t* __restrict__ Vt) {
  int bid = blockIdx.x;              // ((b*4+kv)*64 + sb)
  int sb = bid & 63, kv = (bid >> 6) & 3, b = bid >> 8;
  int s0 = sb << 5;
  __shared__ bf16_t T[128 * 33];
  int tid = threadIdx.x;
#pragma unroll
  for (int i = 0; i < 16; i++) {
    int idx = i * 256 + tid;         // 0..4095
    int r = idx >> 7, d = idx & 127;
    float v = qkv[((size_t)(b * 2048 + s0 + r)) * 5120 + 4608 + (kv << 7) + d];
    T[d * 33 + r] = (__bf16)v;
  }
  __syncthreads();
#pragma unroll
  for (int j = 0; j < 16; j++) {
    int idx = j * 256 + tid;
    int d = idx >> 5, sc = idx & 31;
    Vt[(((size_t)(b * 4 + kv)) * 128 + d) * 2048 + s0 + sc] = T[d * 33 + sc];
  }
}

// ---------------- causal GQA flash attention + sigmoid gate -> ag bf16 (B,S,H*D) ----
// Shared-LDS structure (R10, verified): block = (pair pr, h, b), 4 waves x 16 q-rows,
// two sequential phases (q-block pr, then 31-pr) -> 66 equal kv-tiles per block.
// K/V staged in LDS (32 KB dbuf) via global_load_lds with both-sides XOR swizzle;
// counted vmcnt(4); vmcnt -> barrier -> reads ordering.
__global__ __launch_bounds__(256, 3) void attn(const bf16_t* __restrict__ Qr,
                                               const bf16_t* __restrict__ Kr,
                                               const bf16_t* __restrict__ Vt,
                                               const float* __restrict__ qkv,
                                               bf16_t* __restrict__ ag) {
  __shared__ bf16_t Ks[2][32 * 128];   // 16 KB: K tiles (rows kv, cols d), XOR row&15
  __shared__ bf16_t Vs[2][128 * 32];   // 16 KB: V^T tiles (rows d, cols kv), XOR (d>>1)&3
  int bid = blockIdx.x;                // 512 = 16 pr * (16 h * 2 b)
  int hb = bid & 31;
  int h = hb & 15, b = hb >> 4;
  int pr = bid >> 5;                   // 0..15
  int kvh = h >> 2;
  int tid = threadIdx.x, lane = tid & 63, wv = tid >> 6;
  int lr = lane & 15, g = lane >> 4;
  int r0base = ((lr >> 2) << 3) + (lr & 3);   // pi(lr): A-row -> K-row map

  const bf16_t* Kg = Kr + ((size_t)(b * 4 + kvh)) * 2048 * 128;
  const bf16_t* Vg = Vt + ((size_t)(b * 4 + kvh)) * 128 * 2048;

  auto stage = [&](int buf, int kv0) {
#pragma unroll
    for (int i = 0; i < 2; i++) {      // K: 8 KB, 512 chunks of 16 B
      int c = i * 256 + tid;
      int row = c >> 4, lc = (c & 15) ^ (row & 15);
      __builtin_amdgcn_global_load_lds(
          (const __attribute__((address_space(1))) void*)(Kg + (size_t)(kv0 + row) * 128 + lc * 8),
          (__attribute__((address_space(3))) void*)&Ks[buf][c * 8], 16, 0, 0);
    }
#pragma unroll
    for (int i = 0; i < 2; i++) {      // V: 8 KB
      int c = i * 256 + tid;
      int d = c >> 2, cv = (c & 3) ^ ((d >> 1) & 3);
      __builtin_amdgcn_global_load_lds(
          (const __attribute__((address_space(1))) void*)(Vg + (size_t)d * 2048 + kv0 + cv * 8),
          (__attribute__((address_space(3))) void*)&Vs[buf][c * 8], 16, 0, 0);
    }
  };

  auto sm = [&](const f32x4& s0, const f32x4& s1, int qrow, int kvabs, bool dia,
                float& mrun, float& lsp, bf16x8& pb, f32x4 (&oac)[8]) {
    float tt[8];
#pragma unroll
    for (int r = 0; r < 4; r++) { tt[r] = s0[r]; tt[4 + r] = s1[r]; }
    if (dia) {
#pragma unroll
      for (int r = 0; r < 4; r++) {
        if (kvabs + r > qrow)     tt[r]     = -1e30f;
        if (kvabs + 4 + r > qrow) tt[4 + r] = -1e30f;
      }
    }
    float lm = fmaxf(fmaxf(fmaxf(tt[0], tt[1]), tt[2]),
                     fmaxf(fmaxf(tt[3], tt[4]), fmaxf(fmaxf(tt[5], tt[6]), tt[7])));
    if (__all(lm <= mrun + 8.f)) {      // defer-max common path: lane-local only
      float ps = 0.f;
#pragma unroll
      for (int i = 0; i < 8; i++) {
        float pv = __builtin_amdgcn_exp2f(tt[i] - mrun);
        pb[i] = (__bf16)pv; ps += pv;
      }
      lsp += ps;
    } else {                            // rare rescale path
      float pm = lm;
      pm = fmaxf(pm, __shfl_xor(pm, 16));
      pm = fmaxf(pm, __shfl_xor(pm, 32));
      float mnew = fmaxf(mrun, pm);
      float corr = __builtin_amdgcn_exp2f(mrun - mnew);
      float ps = 0.f;
#pragma unroll
      for (int i = 0; i < 8; i++) {
        float pv = __builtin_amdgcn_exp2f(tt[i] - mnew);
        pb[i] = (__bf16)pv; ps += pv;
      }
      lsp = lsp * corr + ps;
      mrun = mnew;
#pragma unroll
      for (int dt = 0; dt < 8; dt++)
#pragma unroll
        for (int r = 0; r < 4; r++) oac[dt][r] *= corr;
    }
  };

  for (int phase = 0; phase < 2; phase++) {
    int qb = phase ? (31 - pr) : pr;   // 64-row q-block index
    int qw0 = qb << 6;
    int qw = qw0 + (wv << 4);          // wave q base (16 rows)
    int qrow = qw + lr;
    int qmax = qw + 15;
    int nt = (qb + 1) << 1;            // 32-wide kv tiles

    const bf16_t* Qg = Qr + (((size_t)(b * 16 + h)) * 2048 + qrow) * 128;
    bf16x8 qf[4];
#pragma unroll
    for (int ds = 0; ds < 4; ds++) qf[ds] = *(const bf16x8*)(Qg + ds * 32 + g * 8);

    f32x4 oa[8];
#pragma unroll
    for (int i = 0; i < 8; i++)
#pragma unroll
      for (int r = 0; r < 4; r++) oa[i][r] = 0.f;
    float mrun = -1e30f, lsp = 0.f;

    stage(0, 0);
    for (int t = 0; t < nt; t++) {
      int cur = t & 1;
      if (t + 1 < nt) {
        stage(cur ^ 1, (t + 1) << 5);
        asm volatile("s_waitcnt vmcnt(4)" ::: "memory");   // tile t landed; t+1 in flight
      } else {
        asm volatile("s_waitcnt vmcnt(0)" ::: "memory");
      }
      __builtin_amdgcn_s_barrier();
      asm volatile("" ::: "memory");
      int kvb = t << 5;
      if (kvb <= qmax) {
        const bf16_t* kb = Ks[cur];
        const bf16_t* vb = Vs[cur];
        int ra = r0base, rb2 = r0base + 4;
        bf16x8 a0[4], a1[4];
#pragma unroll
        for (int ds = 0; ds < 4; ds++) {
          a0[ds] = *(const bf16x8*)&kb[ra * 128 + (((ds * 4 + g) ^ (ra & 15)) << 3)];
          a1[ds] = *(const bf16x8*)&kb[rb2 * 128 + (((ds * 4 + g) ^ (rb2 & 15)) << 3)];
        }
        f32x4 s0, s1;
#pragma unroll
        for (int r = 0; r < 4; r++) { s0[r] = 0.f; s1[r] = 0.f; }
        __builtin_amdgcn_s_setprio(1);
#pragma unroll
        for (int ds = 0; ds < 4; ds++) {
          s0 = __builtin_amdgcn_mfma_f32_16x16x32_bf16(a0[ds], qf[ds], s0, 0, 0, 0);
          s1 = __builtin_amdgcn_mfma_f32_16x16x32_bf16(a1[ds], qf[ds], s1, 0, 0, 0);
        }
        __builtin_amdgcn_s_setprio(0);
        int kvabs = kvb + (g << 3);
        bool dia = (kvb + 31 > qw);
        bf16x8 pb;
        sm(s0, s1, qrow, kvabs, dia, mrun, lsp, pb, oa);
        __builtin_amdgcn_s_setprio(1);
#pragma unroll
        for (int dt = 0; dt < 8; dt++) {
          int d = dt * 16 + lr;
          bf16x8 va = *(const bf16x8*)&vb[d * 32 + ((g ^ ((d >> 1) & 3)) << 3)];
          oa[dt] = __builtin_amdgcn_mfma_f32_16x16x32_bf16(va, pb, oa[dt], 0, 0, 0);
        }
        __builtin_amdgcn_s_setprio(0);
      }
      asm volatile("s_waitcnt lgkmcnt(0)" ::: "memory");   // my ds_reads done before recycle
      __builtin_amdgcn_s_barrier();
      asm volatile("" ::: "memory");
    }

    float ls = lsp + __shfl_xor(lsp, 16);
    ls += __shfl_xor(ls, 32);
    float invl = __builtin_amdgcn_rcpf(ls);

    size_t ob = ((size_t)b * 2048 + qrow) * 2048 + (h << 7);
    size_t gb = ((size_t)b * 2048 + qrow) * 5120 + 2048 + (h << 7);
#pragma unroll
    for (int dt = 0; dt < 8; dt++) {
      int d = dt * 16 + (g << 2);
      float4 gt = *(const float4*)(qkv + gb + d);
      bf16x4v o;
      o[0] = (__bf16)(oa[dt][0] * invl * __builtin_amdgcn_rcpf(1.f + __builtin_amdgcn_exp2f(-gt.x * LOG2E)));
      o[1] = (__bf16)(oa[dt][1] * invl * __builtin_amdgcn_rcpf(1.f + __builtin_amdgcn_exp2f(-gt.y * LOG2E)));
      o[2] = (__bf16)(oa[dt][2] * invl * __builtin_amdgcn_rcpf(1.f + __builtin_amdgcn_exp2f(-gt.z * LOG2E)));
      o[3] = (__bf16)(oa[dt][3] * invl * __builtin_amdgcn_rcpf(1.f + __builtin_amdgcn_exp2f(-gt.w * LOG2E)));
      *(bf16x4v*)(ag + ob + d) = o;
    }
  }
}

// ---------------- launch ----------------
extern "C" void kernel_launch(void* const* d_in, const int* in_sizes, int n_in,
                              void* d_out, int out_size, void* d_ws, size_t ws_size,
                              hipStream_t stream) {
  const float* x    = (const float*)d_in[0];
  const float* wqkv = (const float*)d_in[1];
  const float* wo   = (const float*)d_in[2];
  const float* qnw  = (const float*)d_in[3];
  const float* qnb  = (const float*)d_in[4];
  const float* knw  = (const float*)d_in[5];
  const float* knb  = (const float*)d_in[6];
  float* out = (float*)d_out;

  char* p = (char*)d_ws;
  bf16_t* xb  = (bf16_t*)p;           // 16 MB, reused as ag after GEMM1
  bf16_t* ag  = xb;
  p += (size_t)16777216;
  bf16_t* wqb = (bf16_t*)p;           // 20 MB, reused as Qr after GEMM1
  bf16_t* Qr  = wqb;
  p += (size_t)20971520;
  bf16_t* wob = (bf16_t*)p; p += (size_t)8388608;
  float*  qkv = (float*)p;  p += (size_t)83886080;
  bf16_t* Kr  = (bf16_t*)p; p += (size_t)4194304;
  bf16_t* Vt  = (bf16_t*)p; p += (size_t)4194304;
  float* cosT = (float*)p;  p += (size_t)524288;
  float* sinT = (float*)p;  p += (size_t)524288;

  cvt_f32_bf16<<<8192, 256, 0, stream>>>(x, xb, 2097152);
  cvt_f32_bf16<<<10240, 256, 0, stream>>>(wqkv, wqb, 2621440);
  cvt_f32_bf16<<<4096, 256, 0, stream>>>(wo, wob, 1048576);
  rope_tables<<<512, 256, 0, stream>>>(cosT, sinT);

  // qkv = x @ w_qkv^T   (4096 x 5120 x K=2048): BM=256, BN=320 -> 256 blocks
  gemm8p<8, 5><<<256, 512, 0, stream>>>(xb, wqb, qkv, 4096, 5120, 2048);

  ln_rope<<<4096, 256, 0, stream>>>(qkv, qnw, qnb, knw, knb, cosT, sinT, Qr, Kr);
  vtrans<<<512, 256, 0, stream>>>(qkv, Vt);

  attn<<<512, 256, 0, stream>>>(Qr, Kr, Vt, qkv, ag);

  // out = ag @ w_o^T    (4096 x 2048 x K=2048): BM=128, BN=256 -> 256 blocks
  gemm8p<4, 4><<<256, 512, 0, stream>>>(ag, wob, out, 4096, 2048, 2048);
}